// Round 2
// baseline (223.618 us; speedup 1.0000x reference)
//
#include <hip/hip_runtime.h>
#include <math.h>

#define BSZ 32
#define NSL 1024
#define HS  768
#define BM  128
#define BK  32
#define NKS (HS / BK)            // 24
#define NTILE (NSL / BM)         // 8
#define TILES_PER_BATCH 36       // upper-tri incl diag of 8x8
#define NWG (BSZ * TILES_PER_BATCH)  // 1152

typedef __attribute__((ext_vector_type(8))) unsigned short u16x8;
typedef __attribute__((ext_vector_type(4))) float f32x4;

__device__ __forceinline__ unsigned short f2bf(float x) {
  unsigned u = __float_as_uint(x);
  unsigned r = (u + 0x7FFFu + ((u >> 16) & 1u)) >> 16;   // round-to-nearest-even
  return (unsigned short)r;
}

__device__ __forceinline__ void gload_lds16(const void* g, void* l) {
  __builtin_amdgcn_global_load_lds((__attribute__((address_space(1))) void*)(void*)g,
                                   (__attribute__((address_space(3))) void*)l, 16, 0, 0);
}

// ---------------- mask dtype detection (bool8 vs int32 vs f32 0/1) -------------
__global__ void detect_kernel(const unsigned int* __restrict__ mraw, int* __restrict__ flag) {
  __shared__ int okInt, okF32;
  if (threadIdx.x == 0) { okInt = 1; okF32 = 1; }
  __syncthreads();
  int badI = 0, badF = 0;
  // scan first 32KB only (safe under every layout interpretation)
  for (int i = threadIdx.x; i < 8192; i += 256) {
    unsigned v = mraw[i];
    if (v != 0u && v != 1u) badI = 1;
    if (v != 0u && v != 0x3F800000u) badF = 1;
  }
  if (badI) atomicAnd(&okInt, 0);
  if (badF) atomicAnd(&okF32, 0);
  __syncthreads();
  if (threadIdx.x == 0) *flag = okInt ? 0 : (okF32 ? 1 : 2);
}

// ------------- canonicalize mask/gt to f32, per-batch pair count ---------------
__global__ __launch_bounds__(256) void convert_kernel(const void* __restrict__ mraw,
                                                      const int* __restrict__ gt,
                                                      const int* __restrict__ flag,
                                                      float* __restrict__ gtf,
                                                      float* __restrict__ maskf,
                                                      float* __restrict__ cnt) {
  int i = blockIdx.x * 256 + threadIdx.x;   // < 32768
  int f = *flag;
  bool m;
  if (f == 0)      m = ((const int*)mraw)[i] != 0;
  else if (f == 1) m = ((const float*)mraw)[i] != 0.0f;
  else             m = ((const unsigned char*)mraw)[i] != 0;
  float mf = m ? 1.0f : 0.0f;
  maskf[i] = mf;
  gtf[i] = (float)gt[i];
  float c = mf;
  #pragma unroll
  for (int off = 32; off; off >>= 1) c += __shfl_down(c, off);
  if ((threadIdx.x & 63) == 0) atomicAdd(&cnt[i >> 10], c);
}

// --------- normalize rows; write bf16 Xn (or just inv-norms if ws small) -------
__global__ __launch_bounds__(256) void norm_kernel(const float* __restrict__ embeds,
                                                   unsigned short* __restrict__ xn,
                                                   float* __restrict__ invn,
                                                   int writeXn) {
  int w = threadIdx.x >> 6, lane = threadIdx.x & 63;
  int row = blockIdx.x * 4 + w;                      // < 32768
  const float* src = embeds + (size_t)row * HS;
  float4 v[3];
  float ss = 0.0f;
  #pragma unroll
  for (int q = 0; q < 3; ++q) {
    v[q] = *(const float4*)(src + q * 256 + lane * 4);
    ss += v[q].x * v[q].x + v[q].y * v[q].y + v[q].z * v[q].z + v[q].w * v[q].w;
  }
  #pragma unroll
  for (int off = 32; off; off >>= 1) ss += __shfl_xor(ss, off);
  float inv = 1.0f / fmaxf(sqrtf(ss), 1e-8f);
  if (writeXn) {
    unsigned short* dst = xn + (size_t)row * HS;
    #pragma unroll
    for (int q = 0; q < 3; ++q) {
      ushort4 h;
      h.x = f2bf(v[q].x * inv); h.y = f2bf(v[q].y * inv);
      h.z = f2bf(v[q].z * inv); h.w = f2bf(v[q].w * inv);
      *(ushort4*)(dst + q * 256 + lane * 4) = h;
    }
  } else if (lane == 0) {
    invn[row] = inv;
  }
}

// ---------------- fused Gram + masked relative-loss reduction ------------------
// One WG per (batch, upper-tri 128x128 tile pair). 4 waves in 2x2, each owns a
// 64x64 sub-tile as 4x4 frags of 16x16x32 bf16 MFMA. LDS tiles [128][BK] bf16
// with 16B-chunk XOR swizzle: chunk c of row r stored at pos c ^ ((r>>1)&3)
// (applied on the pre-swizzled GLOBAL source so global_load_lds dest stays
// linear; same XOR on the ds_read side).
template<int STAGE_F32>
__global__ __launch_bounds__(256) void gram_kernel(const float* __restrict__ embeds,
                                                   const unsigned short* __restrict__ xn,
                                                   const float* __restrict__ invn,
                                                   const float* __restrict__ gtf,
                                                   const float* __restrict__ maskf,
                                                   float* __restrict__ num) {
  __shared__ __align__(16) unsigned short lA[BM * BK];   // 8 KB
  __shared__ __align__(16) unsigned short lB[BM * BK];   // 8 KB
  __shared__ float gtR[BM], gtC[BM], mR[BM], mC[BM], ivR[BM], ivC[BM];
  __shared__ float red[4];

  // XCD-aware swizzle (NWG % 8 == 0 -> bijective): contiguous tiles per XCD
  int blk = blockIdx.x;
  int swz = (blk & 7) * (NWG / 8) + (blk >> 3);
  int b = swz / TILES_PER_BATCH;
  int t = swz % TILES_PER_BATCH;
  int ti = 0;
  { int c = NTILE; while (t >= c) { t -= c; --c; ++ti; } }
  int tj = ti + t;

  const int tid = threadIdx.x;
  const int w = tid >> 6;
  const int lane = tid & 63;
  const int wr = w >> 1, wc = w & 1;
  const int Ra = ti * BM, Rb = tj * BM;

  if (tid < BM) {
    int ia = b * NSL + Ra + tid;
    int ib = b * NSL + Rb + tid;
    gtR[tid] = gtf[ia]; mR[tid] = maskf[ia];
    gtC[tid] = gtf[ib]; mC[tid] = maskf[ib];
    if constexpr (STAGE_F32 != 0) { ivR[tid] = invn[ia]; ivC[tid] = invn[ib]; }
  }
  __syncthreads();

  f32x4 acc[4][4];
  #pragma unroll
  for (int m = 0; m < 4; ++m)
    #pragma unroll
    for (int n = 0; n < 4; ++n)
      #pragma unroll
      for (int r = 0; r < 4; ++r) acc[m][n][r] = 0.0f;

  for (int ks = 0; ks < NKS; ++ks) {
    const int kbase = ks * BK;
    if constexpr (STAGE_F32 == 0) {
      #pragma unroll
      for (int q = 0; q < 2; ++q) {
        int L = q * 256 + tid;            // linear 16B-chunk index 0..511
        int row = L >> 2, pos = L & 3;
        int c = pos ^ ((row >> 1) & 3);   // pre-swizzled global source
        const unsigned short* gaA = xn + (size_t)(b * NSL + Ra + row) * HS + kbase + c * 8;
        const unsigned short* gaB = xn + (size_t)(b * NSL + Rb + row) * HS + kbase + c * 8;
        unsigned short* ldA = &lA[(q * 256 + w * 64) * 8];  // wave-uniform base
        unsigned short* ldB = &lB[(q * 256 + w * 64) * 8];
        gload_lds16(gaA, ldA);
        gload_lds16(gaB, ldB);
      }
    } else {
      #pragma unroll
      for (int q = 0; q < 2; ++q) {
        int L = q * 256 + tid;
        int row = L >> 2, pos = L & 3;
        int c = pos ^ ((row >> 1) & 3);
        const float* gaA = embeds + (size_t)(b * NSL + Ra + row) * HS + kbase + c * 8;
        const float* gaB = embeds + (size_t)(b * NSL + Rb + row) * HS + kbase + c * 8;
        float4 a0 = *(const float4*)gaA;
        float4 a1 = *(const float4*)(gaA + 4);
        float4 b0 = *(const float4*)gaB;
        float4 b1 = *(const float4*)(gaB + 4);
        float sa = ivR[row], sb = ivC[row];
        u16x8 ha, hb;
        ha[0] = f2bf(a0.x * sa); ha[1] = f2bf(a0.y * sa);
        ha[2] = f2bf(a0.z * sa); ha[3] = f2bf(a0.w * sa);
        ha[4] = f2bf(a1.x * sa); ha[5] = f2bf(a1.y * sa);
        ha[6] = f2bf(a1.z * sa); ha[7] = f2bf(a1.w * sa);
        hb[0] = f2bf(b0.x * sb); hb[1] = f2bf(b0.y * sb);
        hb[2] = f2bf(b0.z * sb); hb[3] = f2bf(b0.w * sb);
        hb[4] = f2bf(b1.x * sb); hb[5] = f2bf(b1.y * sb);
        hb[6] = f2bf(b1.z * sb); hb[7] = f2bf(b1.w * sb);
        *(u16x8*)&lA[row * BK + pos * 8] = ha;
        *(u16x8*)&lB[row * BK + pos * 8] = hb;
      }
    }
    __syncthreads();   // staging complete (drains vmcnt/lgkmcnt before barrier)

    u16x8 af[4], bfv[4];
    const int kc = lane >> 4;
    #pragma unroll
    for (int m = 0; m < 4; ++m) {
      int row = wr * 64 + m * 16 + (lane & 15);
      af[m] = *(const u16x8*)&lA[row * BK + ((kc ^ ((row >> 1) & 3)) * 8)];
    }
    #pragma unroll
    for (int n = 0; n < 4; ++n) {
      int row = wc * 64 + n * 16 + (lane & 15);
      bfv[n] = *(const u16x8*)&lB[row * BK + ((kc ^ ((row >> 1) & 3)) * 8)];
    }
    #pragma unroll
    for (int m = 0; m < 4; ++m)
      #pragma unroll
      for (int n = 0; n < 4; ++n)
        asm volatile("v_mfma_f32_16x16x32_bf16 %0, %1, %2, %0"
                     : "+v"(acc[m][n]) : "v"(af[m]), "v"(bfv[n]));
    __syncthreads();   // compute done before next stage overwrites
  }

  asm volatile("s_nop 7\n\ts_nop 7");   // MFMA->VALU read hazard insurance

  // fused epilogue: D layout col=lane&15, row=(lane>>4)*4+reg (verified m89/m91)
  float lsum = 0.0f;
  const bool diag = (ti == tj);
  #pragma unroll
  for (int m = 0; m < 4; ++m) {
    #pragma unroll
    for (int n = 0; n < 4; ++n) {
      int ljl = wc * 64 + n * 16 + (lane & 15);
      float gj = gtC[ljl], mj = mC[ljl];
      #pragma unroll
      for (int r = 0; r < 4; ++r) {
        int lil = wr * 64 + m * 16 + (lane >> 4) * 4 + r;
        float gi = gtR[lil], mi_ = mR[lil];
        float cosd = 1.0f - acc[m][n][r];
        float vd = 2.0f * fabsf(gi - gj) / (fabsf(gi) + fabsf(gj) + 1e-18f);
        float d = cosd - vd;
        float pm = mi_ * mj;
        if (diag) pm = (lil < ljl) ? pm : 0.0f;   // strict upper triangle
        lsum += d * d * pm;
      }
    }
  }
  #pragma unroll
  for (int off = 32; off; off >>= 1) lsum += __shfl_down(lsum, off);
  if (lane == 0) red[w] = lsum;
  __syncthreads();
  if (tid == 0) atomicAdd(&num[b], red[0] + red[1] + red[2] + red[3]);
}

// ------------------------------- finish ---------------------------------------
__global__ void final_kernel(const float* __restrict__ num, const float* __restrict__ cnt,
                             float* __restrict__ out) {
  int l = threadIdx.x;
  float v = 0.0f;
  if (l < BSZ) {
    float c = cnt[l];
    float den = 0.5f * c * (c - 1.0f) + 1e-13f;   // C(m,2) == sum of pair_mask
    v = sqrtf(num[l] / den);
  }
  #pragma unroll
  for (int off = 32; off; off >>= 1) v += __shfl_down(v, off);
  if (l == 0) out[0] = v * (1.0f / 32.0f);
}

extern "C" void kernel_launch(void* const* d_in, const int* in_sizes, int n_in,
                              void* d_out, int out_size, void* d_ws, size_t ws_size,
                              hipStream_t stream) {
  const float* embeds = (const float*)d_in[0];
  const int* gt = (const int*)d_in[1];
  const void* mask = d_in[2];
  float* out = (float*)d_out;

  char* ws = (char*)d_ws;
  float* num   = (float*)(ws + 0);                 // 32 f32
  float* cnt   = (float*)(ws + 128);               // 32 f32
  int*   flag  = (int*)(ws + 256);
  float* gtf   = (float*)(ws + 512);               // 128 KB
  float* maskf = (float*)(ws + 512 + 131072);      // 128 KB
  float* invn  = (float*)(ws + 512 + 262144);      // 128 KB
  unsigned short* xn = (unsigned short*)(ws + 512 + 393216);  // 48 MB, 16B aligned
  const size_t need_xn = 512 + 393216 + (size_t)BSZ * NSL * HS * 2;

  hipMemsetAsync(d_ws, 0, 512, stream);
  detect_kernel<<<1, 256, 0, stream>>>((const unsigned int*)mask, flag);
  convert_kernel<<<BSZ * NSL / 256, 256, 0, stream>>>(mask, gt, flag, gtf, maskf, cnt);

  int useXn = (ws_size >= need_xn) ? 1 : 0;
  norm_kernel<<<BSZ * NSL / 4, 256, 0, stream>>>(embeds, xn, invn, useXn);
  if (useXn)
    gram_kernel<0><<<NWG, 256, 0, stream>>>(embeds, xn, invn, gtf, maskf, num);
  else
    gram_kernel<1><<<NWG, 256, 0, stream>>>(embeds, xn, invn, gtf, maskf, num);
  final_kernel<<<1, 64, 0, stream>>>(num, cnt, out);
}